// Round 3
// baseline (1624.534 us; speedup 1.0000x reference)
//
#include <hip/hip_runtime.h>

#define NPTS 131072
#define DIM  128
#define KC   1024
#define MARGIN 0.05f

using bfrag = __attribute__((ext_vector_type(8))) short;   // 8 bf16 = 4 VGPRs
using f32x4 = __attribute__((ext_vector_type(4))) float;

static __device__ __forceinline__ unsigned short f2bf(float f) {
    unsigned int u = __float_as_uint(f);
    u += 0x7FFFu + ((u >> 16) & 1u);
    return (unsigned short)(u >> 16);
}
static __device__ __forceinline__ float bf2f(unsigned short h) {
    return __uint_as_float(((unsigned int)h) << 16);
}

// ---------------- prep: exact 0.5*||e||^2 ----------------
__global__ void vq_ee(const float* __restrict__ emb, float* __restrict__ ee) {
    int gid  = blockIdx.x * blockDim.x + threadIdx.x;
    int w    = gid >> 6;          // code id (1024 waves)
    int lane = threadIdx.x & 63;
    const float* e = emb + (size_t)w * DIM;
    float a = e[lane];
    float b = e[lane + 64];
    float v = a * a + b * b;
    #pragma unroll
    for (int o = 32; o > 0; o >>= 1) v += __shfl_down(v, o);
    if (lane == 0) ee[w] = 0.5f * v;
}

// ---------------- prep: bf16 hi/lo codebook image, pre-swizzled for LDS ----
// LDS tile per 64-code chunk: 32KB = [16KB hi][16KB lo]; row r' (code&63) at
// byte r'*256, element k at byte (2k)^((r'&7)<<4). Image is the linear LDS
// content so global_load_lds can copy it verbatim.
__global__ void vq_prep(const float* __restrict__ emb, unsigned short* __restrict__ wsE) {
    int t = blockIdx.x * 256 + threadIdx.x;      // 0..131071
    int code = t >> 7, k = t & 127;
    float v = emb[(size_t)code * DIM + k];
    unsigned short h = f2bf(v);
    unsigned short l = f2bf(v - bf2f(h));
    int chunk = code >> 6, r = code & 63;
    int o = (r << 8) + (((k << 1)) ^ ((r & 7) << 4));   // byte offset in hi region
    size_t base = (size_t)chunk * 32768;
    wsE[(base + (size_t)o) >> 1]          = h;
    wsE[(base + 16384 + (size_t)o) >> 1]  = l;
}

// ---------------- pass A: MFMA scores + top-2 argmax ----------------
__global__ __launch_bounds__(256, 3) void vq_mfma(const float* __restrict__ x,
                                                  const unsigned short* __restrict__ wsE,
                                                  const float* __restrict__ ee,
                                                  int* __restrict__ best) {
    __shared__ __attribute__((aligned(128))) unsigned short lds[16384]; // 32 KB
    const int tid  = threadIdx.x;
    const int lane = tid & 63, wv = tid >> 6;
    const int g    = lane >> 4, c = lane & 15;
    const int blockbase = blockIdx.x * 128;

    // A-fragments (x rows) in registers: row = blockbase + wv*32 + rt*16 + c,
    // k-slot set for lane-group g: {kc*32 + g*8 .. +8}
    bfrag ah[2][4], al[2][4];
    #pragma unroll
    for (int rt = 0; rt < 2; ++rt) {
        int row = blockbase + wv * 32 + rt * 16 + c;
        const float* xr = x + (size_t)row * DIM;
        #pragma unroll
        for (int kc = 0; kc < 4; ++kc) {
            const float4* p = reinterpret_cast<const float4*>(xr + kc * 32 + g * 8);
            float4 v0 = p[0], v1 = p[1];
            float vv[8] = {v0.x, v0.y, v0.z, v0.w, v1.x, v1.y, v1.z, v1.w};
            bfrag h, l;
            #pragma unroll
            for (int j = 0; j < 8; ++j) {
                unsigned short hu = f2bf(vv[j]);
                unsigned short lu = f2bf(vv[j] - bf2f(hu));
                h[j] = (short)hu; l[j] = (short)lu;
            }
            ah[rt][kc] = h; al[rt][kc] = l;
        }
    }

    float b1[2][4], b2[2][4]; int i1[2][4];
    #pragma unroll
    for (int rt = 0; rt < 2; ++rt)
        #pragma unroll
        for (int q = 0; q < 4; ++q) { b1[rt][q] = -1e30f; b2[rt][q] = -1e30f; i1[rt][q] = 0; }

    for (int ch = 0; ch < 16; ++ch) {
        __syncthreads();   // previous chunk's reads done
        // stage 32 KB chunk: wave wv copies LDS bytes [wv*8192, +8192)
        {
            const char* src = (const char*)wsE + (size_t)ch * 32768 + (size_t)wv * 8192;
            #pragma unroll
            for (int it = 0; it < 8; ++it) {
                __builtin_amdgcn_global_load_lds(
                    (const __attribute__((address_space(1))) void*)(src + it * 1024 + lane * 16),
                    (__attribute__((address_space(3))) void*)((char*)lds + wv * 8192 + it * 1024),
                    16, 0, 0);
            }
        }
        __syncthreads();   // compiler drains vmcnt before barrier

        #pragma unroll
        for (int ct = 0; ct < 4; ++ct) {
            const int r   = ct * 16 + c;          // code row within chunk
            const int swz = (r & 7) << 4;
            f32x4 acc0 = {0.f, 0.f, 0.f, 0.f};
            f32x4 acc1 = {0.f, 0.f, 0.f, 0.f};
            #pragma unroll
            for (int kc = 0; kc < 4; ++kc) {
                int bo = (r << 8) + (((kc << 6) + (g << 4)) ^ swz);
                bfrag bh = *reinterpret_cast<const bfrag*>((const char*)lds + bo);
                bfrag bl = *reinterpret_cast<const bfrag*>((const char*)lds + 16384 + bo);
                acc0 = __builtin_amdgcn_mfma_f32_16x16x32_bf16(ah[0][kc], bh, acc0, 0, 0, 0);
                acc1 = __builtin_amdgcn_mfma_f32_16x16x32_bf16(ah[1][kc], bh, acc1, 0, 0, 0);
                acc0 = __builtin_amdgcn_mfma_f32_16x16x32_bf16(al[0][kc], bh, acc0, 0, 0, 0);
                acc1 = __builtin_amdgcn_mfma_f32_16x16x32_bf16(al[1][kc], bh, acc1, 0, 0, 0);
                acc0 = __builtin_amdgcn_mfma_f32_16x16x32_bf16(ah[0][kc], bl, acc0, 0, 0, 0);
                acc1 = __builtin_amdgcn_mfma_f32_16x16x32_bf16(ah[1][kc], bl, acc1, 0, 0, 0);
            }
            const int code = ch * 64 + ct * 16 + c;
            const float eec = ee[code];
            #pragma unroll
            for (int q = 0; q < 4; ++q) {
                float s0 = acc0[q] - eec;
                bool gt0 = s0 > b1[0][q];
                b2[0][q] = gt0 ? b1[0][q] : fmaxf(b2[0][q], s0);
                i1[0][q] = gt0 ? code    : i1[0][q];
                b1[0][q] = gt0 ? s0      : b1[0][q];
                float s1 = acc1[q] - eec;
                bool gt1 = s1 > b1[1][q];
                b2[1][q] = gt1 ? b1[1][q] : fmaxf(b2[1][q], s1);
                i1[1][q] = gt1 ? code    : i1[1][q];
                b1[1][q] = gt1 ? s1      : b1[1][q];
            }
        }
    }

    // cross-lane top-2 reduce over the 16 cols (codes) in each 16-lane group
    #pragma unroll
    for (int rt = 0; rt < 2; ++rt) {
        #pragma unroll
        for (int q = 0; q < 4; ++q) {
            float v1 = b1[rt][q], v2 = b2[rt][q]; int ii = i1[rt][q];
            #pragma unroll
            for (int m = 1; m < 16; m <<= 1) {
                float o1 = __shfl_xor(v1, m, 64);
                int   oi = __shfl_xor(ii, m, 64);
                float o2 = __shfl_xor(v2, m, 64);
                bool take = (o1 > v1) || (o1 == v1 && oi < ii);
                float nb2 = fmaxf(fminf(v1, o1), fmaxf(v2, o2));
                v1 = take ? o1 : v1;
                ii = take ? oi : ii;
                v2 = nb2;
            }
            if (c == 0) {
                int row = blockbase + wv * 32 + rt * 16 + g * 4 + q;
                int pack = ii | (((v1 - v2) < MARGIN) ? 0x40000000 : 0);
                best[row] = pack;
            }
        }
    }
}

// ---------------- pass B: finalize (+rare exact fp32 rescan) ----------------
__global__ void vq_fin(const float* __restrict__ x, const float* __restrict__ emb,
                       const float* __restrict__ ee, const int* __restrict__ best,
                       float* __restrict__ out, float* __restrict__ bsum) {
    const int p = blockIdx.x * 256 + threadIdx.x;

    float4 xr[32];
    const float4* xv = reinterpret_cast<const float4*>(x + (size_t)p * DIM);
    #pragma unroll
    for (int i = 0; i < 32; ++i) xr[i] = xv[i];

    int pk = best[p];
    int idx = pk & 0x3FFFFFFF;
    if (pk & 0x40000000) {   // marginal gap: exact fp32 rescan, first-min tie-break
        float bv = -3.4e38f; int bi = 0;
        for (int k = 0; k < KC; ++k) {
            const float4* e4 = reinterpret_cast<const float4*>(emb + (size_t)k * DIM);
            float a0 = 0.f, a1 = 0.f, a2 = 0.f, a3 = 0.f;
            #pragma unroll
            for (int i = 0; i < 32; ++i) {
                float4 ev = e4[i];
                a0 = fmaf(xr[i].x, ev.x, a0);
                a1 = fmaf(xr[i].y, ev.y, a1);
                a2 = fmaf(xr[i].z, ev.z, a2);
                a3 = fmaf(xr[i].w, ev.w, a3);
            }
            float s = ((a0 + a1) + (a2 + a3)) - ee[k];
            if (s > bv) { bv = s; bi = k; }
        }
        idx = bi;
    }

    out[p] = (float)idx;

    const float4* q4 = reinterpret_cast<const float4*>(emb + (size_t)idx * DIM);
    float4* oq = reinterpret_cast<float4*>(out + (size_t)NPTS + (size_t)p * DIM);
    float lsum = 0.f;
    #pragma unroll
    for (int i = 0; i < 32; ++i) {
        float4 qv = q4[i];
        oq[i] = qv;
        float dx = qv.x - xr[i].x;
        float dy = qv.y - xr[i].y;
        float dz = qv.z - xr[i].z;
        float dw = qv.w - xr[i].w;
        lsum += dx * dx + dy * dy + dz * dz + dw * dw;
    }
    __shared__ float red[4];
    #pragma unroll
    for (int o = 32; o > 0; o >>= 1) lsum += __shfl_down(lsum, o);
    int lane = threadIdx.x & 63, wvl = threadIdx.x >> 6;
    if (lane == 0) red[wvl] = lsum;
    __syncthreads();
    if (threadIdx.x == 0) bsum[blockIdx.x] = (red[0] + red[1]) + (red[2] + red[3]);
}

__global__ void vq_finalize(const float* __restrict__ bsum, float* __restrict__ out) {
    __shared__ float red[8];
    int t = threadIdx.x;  // 512 threads
    float v = bsum[t];
    #pragma unroll
    for (int o = 32; o > 0; o >>= 1) v += __shfl_down(v, o);
    if ((t & 63) == 0) red[t >> 6] = v;
    __syncthreads();
    if (t == 0) {
        float s = 0.f;
        #pragma unroll
        for (int i = 0; i < 8; ++i) s += red[i];
        out[(size_t)NPTS + (size_t)NPTS * DIM] = 1.25f * s / 16777216.0f;
    }
}

// ---------------- fallback (round-2 proven path) ----------------
__global__ __launch_bounds__(256, 1) void vq_main(const float* __restrict__ x,
                                                  const float* __restrict__ emb,
                                                  const float* __restrict__ ee,
                                                  float* __restrict__ out,
                                                  float* __restrict__ bsum) {
    const int p = blockIdx.x * 256 + threadIdx.x;
    float4 xr[32];
    const float4* xv = reinterpret_cast<const float4*>(x + (size_t)p * DIM);
    #pragma unroll
    for (int i = 0; i < 32; ++i) xr[i] = xv[i];
    float bestv = -3.4e38f; int bi = 0;
    for (int k = 0; k < KC; ++k) {
        const int ku = __builtin_amdgcn_readfirstlane(k);
        const float4* e4 = reinterpret_cast<const float4*>(emb + (size_t)ku * DIM);
        float a0 = 0.f, a1 = 0.f, a2 = 0.f, a3 = 0.f;
        #pragma unroll
        for (int i = 0; i < 32; ++i) {
            float4 ev = e4[i];
            a0 = fmaf(xr[i].x, ev.x, a0);
            a1 = fmaf(xr[i].y, ev.y, a1);
            a2 = fmaf(xr[i].z, ev.z, a2);
            a3 = fmaf(xr[i].w, ev.w, a3);
        }
        float s = ((a0 + a1) + (a2 + a3)) - ee[ku];
        if (s > bestv) { bestv = s; bi = k; }
    }
    out[p] = (float)bi;
    const float4* q4 = reinterpret_cast<const float4*>(emb + (size_t)bi * DIM);
    float4* oq = reinterpret_cast<float4*>(out + (size_t)NPTS + (size_t)p * DIM);
    float lsum = 0.f;
    #pragma unroll
    for (int i = 0; i < 32; ++i) {
        float4 qv = q4[i];
        oq[i] = qv;
        float dx = qv.x - xr[i].x;
        float dy = qv.y - xr[i].y;
        float dz = qv.z - xr[i].z;
        float dw = qv.w - xr[i].w;
        lsum += dx * dx + dy * dy + dz * dz + dw * dw;
    }
    __shared__ float red[4];
    #pragma unroll
    for (int o = 32; o > 0; o >>= 1) lsum += __shfl_down(lsum, o);
    int lane = threadIdx.x & 63, wvl = threadIdx.x >> 6;
    if (lane == 0) red[wvl] = lsum;
    __syncthreads();
    if (threadIdx.x == 0) bsum[blockIdx.x] = (red[0] + red[1]) + (red[2] + red[3]);
}

extern "C" void kernel_launch(void* const* d_in, const int* in_sizes, int n_in,
                              void* d_out, int out_size, void* d_ws, size_t ws_size,
                              hipStream_t stream) {
    const float* x   = (const float*)d_in[0];
    const float* emb = (const float*)d_in[1];
    float* out = (float*)d_out;
    char*  ws  = (char*)d_ws;

    if (ws_size >= 1054720) {
        unsigned short* wsE = (unsigned short*)ws;          // 512 KB image
        float* ee   = (float*)(ws + 524288);                // 4 KB
        int*   best = (int*)(ws + 528384);                  // 512 KB
        float* bsum = (float*)(ws + 1052672);               // 2 KB
        vq_prep<<<512, 256, 0, stream>>>(emb, wsE);
        vq_ee<<<256, 256, 0, stream>>>(emb, ee);
        vq_mfma<<<1024, 256, 0, stream>>>(x, wsE, ee, best);
        vq_fin<<<512, 256, 0, stream>>>(x, emb, ee, best, out, bsum);
        vq_finalize<<<1, 512, 0, stream>>>(bsum, out);
    } else {
        float* ee   = (float*)ws;
        float* bsum = (float*)ws + 1024;
        vq_ee<<<256, 256, 0, stream>>>(emb, ee);
        vq_main<<<512, 256, 0, stream>>>(x, emb, ee, out, bsum);
        vq_finalize<<<1, 512, 0, stream>>>(bsum, out);
    }
}

// Round 4
// 180.331 us; speedup vs baseline: 9.0086x; 9.0086x over previous
//
#include <hip/hip_runtime.h>

#define NPTS 131072
#define DIM  128
#define KC   1024

using bfrag = __attribute__((ext_vector_type(8))) short;   // 8 bf16 = 4 VGPRs
using f32x4 = __attribute__((ext_vector_type(4))) float;

static __device__ __forceinline__ unsigned short f2bf(float f) {
    unsigned int u = __float_as_uint(f);
    u += 0x7FFFu + ((u >> 16) & 1u);
    return (unsigned short)(u >> 16);
}
static __device__ __forceinline__ float bf2f(unsigned short h) {
    return __uint_as_float(((unsigned int)h) << 16);
}

// ---------------- prep: exact 0.5*||e||^2 ----------------
__global__ void vq_ee(const float* __restrict__ emb, float* __restrict__ ee) {
    int gid  = blockIdx.x * blockDim.x + threadIdx.x;
    int w    = gid >> 6;          // code id (1024 waves)
    int lane = threadIdx.x & 63;
    const float* e = emb + (size_t)w * DIM;
    float a = e[lane];
    float b = e[lane + 64];
    float v = a * a + b * b;
    #pragma unroll
    for (int o = 32; o > 0; o >>= 1) v += __shfl_down(v, o);
    if (lane == 0) ee[w] = 0.5f * v;
}

// ---------------- prep: bf16 hi/lo codebook image, pre-swizzled for LDS ----
// LDS tile per 64-code chunk: 32KB = [16KB hi][16KB lo]; row r' (code&63) at
// byte r'*256, element k at byte (2k)^((r'&7)<<4). Image is the linear LDS
// content so global_load_lds can copy it verbatim.
__global__ void vq_prep(const float* __restrict__ emb, unsigned short* __restrict__ wsE) {
    int t = blockIdx.x * 256 + threadIdx.x;      // 0..131071
    int code = t >> 7, k = t & 127;
    float v = emb[(size_t)code * DIM + k];
    unsigned short h = f2bf(v);
    unsigned short l = f2bf(v - bf2f(h));
    int chunk = code >> 6, r = code & 63;
    int o = (r << 8) + (((k << 1)) ^ ((r & 7) << 4));   // byte offset in hi region
    size_t base = (size_t)chunk * 32768;
    wsE[(base + (size_t)o) >> 1]          = h;
    wsE[(base + 16384 + (size_t)o) >> 1]  = l;
}

// ---------------- pass A: MFMA scores + top-2 (values AND indices) --------
__global__ __launch_bounds__(256, 3) void vq_mfma(const float* __restrict__ x,
                                                  const unsigned short* __restrict__ wsE,
                                                  const float* __restrict__ ee,
                                                  int* __restrict__ best) {
    __shared__ __attribute__((aligned(128))) unsigned short lds[16384]; // 32 KB
    const int tid  = threadIdx.x;
    const int lane = tid & 63, wv = tid >> 6;
    const int g    = lane >> 4, c = lane & 15;
    const int blockbase = blockIdx.x * 128;

    // A-fragments (x rows): row = blockbase + wv*32 + rt*16 + c,
    // k-slots for lane-group g: {kc*32 + g*8 .. +8}
    bfrag ah[2][4], al[2][4];
    #pragma unroll
    for (int rt = 0; rt < 2; ++rt) {
        int row = blockbase + wv * 32 + rt * 16 + c;
        const float* xr = x + (size_t)row * DIM;
        #pragma unroll
        for (int kc = 0; kc < 4; ++kc) {
            const float4* p = reinterpret_cast<const float4*>(xr + kc * 32 + g * 8);
            float4 v0 = p[0], v1 = p[1];
            float vv[8] = {v0.x, v0.y, v0.z, v0.w, v1.x, v1.y, v1.z, v1.w};
            bfrag h, l;
            #pragma unroll
            for (int j = 0; j < 8; ++j) {
                unsigned short hu = f2bf(vv[j]);
                unsigned short lu = f2bf(vv[j] - bf2f(hu));
                h[j] = (short)hu; l[j] = (short)lu;
            }
            ah[rt][kc] = h; al[rt][kc] = l;
        }
    }

    float b1[2][4], b2[2][4]; int i1[2][4], i2[2][4];
    #pragma unroll
    for (int rt = 0; rt < 2; ++rt)
        #pragma unroll
        for (int q = 0; q < 4; ++q) {
            b1[rt][q] = -1e30f; b2[rt][q] = -1e30f;
            i1[rt][q] = 0;      i2[rt][q] = 1;
        }

    for (int ch = 0; ch < 16; ++ch) {
        __syncthreads();   // previous chunk's reads done
        {
            const char* src = (const char*)wsE + (size_t)ch * 32768 + (size_t)wv * 8192;
            #pragma unroll
            for (int it = 0; it < 8; ++it) {
                __builtin_amdgcn_global_load_lds(
                    (const __attribute__((address_space(1))) void*)(src + it * 1024 + lane * 16),
                    (__attribute__((address_space(3))) void*)((char*)lds + wv * 8192 + it * 1024),
                    16, 0, 0);
            }
        }
        __syncthreads();   // vmcnt drained before barrier

        #pragma unroll
        for (int ct = 0; ct < 4; ++ct) {
            const int r   = ct * 16 + c;          // code row within chunk
            const int swz = (r & 7) << 4;
            f32x4 acc0 = {0.f, 0.f, 0.f, 0.f};
            f32x4 acc1 = {0.f, 0.f, 0.f, 0.f};
            #pragma unroll
            for (int kc = 0; kc < 4; ++kc) {
                int bo = (r << 8) + (((kc << 6) + (g << 4)) ^ swz);
                bfrag bh = *reinterpret_cast<const bfrag*>((const char*)lds + bo);
                bfrag bl = *reinterpret_cast<const bfrag*>((const char*)lds + 16384 + bo);
                acc0 = __builtin_amdgcn_mfma_f32_16x16x32_bf16(ah[0][kc], bh, acc0, 0, 0, 0);
                acc1 = __builtin_amdgcn_mfma_f32_16x16x32_bf16(ah[1][kc], bh, acc1, 0, 0, 0);
                acc0 = __builtin_amdgcn_mfma_f32_16x16x32_bf16(al[0][kc], bh, acc0, 0, 0, 0);
                acc1 = __builtin_amdgcn_mfma_f32_16x16x32_bf16(al[1][kc], bh, acc1, 0, 0, 0);
                acc0 = __builtin_amdgcn_mfma_f32_16x16x32_bf16(ah[0][kc], bl, acc0, 0, 0, 0);
                acc1 = __builtin_amdgcn_mfma_f32_16x16x32_bf16(ah[1][kc], bl, acc1, 0, 0, 0);
            }
            const int code = ch * 64 + ct * 16 + c;
            const float eec = ee[code];
            #pragma unroll
            for (int rt = 0; rt < 2; ++rt) {
                float s = (rt == 0 ? acc0[0] : acc1[0]);  // placeholder, overwritten below
                (void)s;
            }
            #pragma unroll
            for (int q = 0; q < 4; ++q) {
                {
                    float s = acc0[q] - eec;
                    bool gt = s > b1[0][q];
                    bool mid = !gt && (s > b2[0][q]);
                    b2[0][q] = gt ? b1[0][q] : (mid ? s : b2[0][q]);
                    i2[0][q] = gt ? i1[0][q] : (mid ? code : i2[0][q]);
                    b1[0][q] = gt ? s : b1[0][q];
                    i1[0][q] = gt ? code : i1[0][q];
                }
                {
                    float s = acc1[q] - eec;
                    bool gt = s > b1[1][q];
                    bool mid = !gt && (s > b2[1][q]);
                    b2[1][q] = gt ? b1[1][q] : (mid ? s : b2[1][q]);
                    i2[1][q] = gt ? i1[1][q] : (mid ? code : i2[1][q]);
                    b1[1][q] = gt ? s : b1[1][q];
                    i1[1][q] = gt ? code : i1[1][q];
                }
            }
        }
    }

    // cross-lane top-2 (value,index) merge over the 16 cols in each group
    #pragma unroll
    for (int rt = 0; rt < 2; ++rt) {
        #pragma unroll
        for (int q = 0; q < 4; ++q) {
            float v1 = b1[rt][q], v2 = b2[rt][q];
            int   ii = i1[rt][q], jj = i2[rt][q];
            #pragma unroll
            for (int m = 1; m < 16; m <<= 1) {
                float o1 = __shfl_xor(v1, m, 64);
                int   oi = __shfl_xor(ii, m, 64);
                float o2 = __shfl_xor(v2, m, 64);
                int   oj = __shfl_xor(jj, m, 64);
                bool take = (o1 > v1) || (o1 == v1 && oi < ii);
                float n1 = take ? o1 : v1;
                int   ni = take ? oi : ii;
                // runner-up candidates: the loser of the top compare, and both old seconds
                float ca = take ? v1 : o1;   int cai = take ? ii : oi;
                float cb = take ? o2 : v2;   int cbi = take ? oj : jj;
                bool sb = (cb > ca) || (cb == ca && cbi < cai);
                float n2 = sb ? cb : ca;
                int   nj = sb ? cbi : cai;
                v1 = n1; ii = ni; v2 = n2; jj = nj;
            }
            if (c == 0) {
                int row = blockbase + wv * 32 + rt * 16 + g * 4 + q;
                best[row] = (ii & 1023) | ((jj & 1023) << 10);
            }
        }
    }
}

// ---------------- pass B: exact fp32 compare of top-2, gather, loss -------
__global__ __launch_bounds__(256) void vq_fin(const float* __restrict__ x,
                                              const float* __restrict__ emb,
                                              const int* __restrict__ best,
                                              float* __restrict__ out,
                                              float* __restrict__ bsum) {
    const int p = blockIdx.x * 256 + threadIdx.x;

    float4 xr[32];
    const float4* xv = reinterpret_cast<const float4*>(x + (size_t)p * DIM);
    #pragma unroll
    for (int i = 0; i < 32; ++i) xr[i] = xv[i];

    int pk = best[p];
    int ia = pk & 1023;
    int ib = (pk >> 10) & 1023;

    // exact fp32 squared distances to the two candidates (codebook is L2-hot)
    const float4* ea = reinterpret_cast<const float4*>(emb + (size_t)ia * DIM);
    const float4* eb = reinterpret_cast<const float4*>(emb + (size_t)ib * DIM);
    float da0 = 0.f, da1 = 0.f, db0 = 0.f, db1 = 0.f;
    #pragma unroll
    for (int i = 0; i < 32; ++i) {
        float4 va = ea[i], vb = eb[i], xx = xr[i];
        float ax = va.x - xx.x, ay = va.y - xx.y, az = va.z - xx.z, aw = va.w - xx.w;
        float bx = vb.x - xx.x, by = vb.y - xx.y, bz = vb.z - xx.z, bw = vb.w - xx.w;
        da0 += ax * ax + ay * ay;  da1 += az * az + aw * aw;
        db0 += bx * bx + by * by;  db1 += bz * bz + bw * bw;
    }
    float da = da0 + da1, db = db0 + db1;
    int idx;
    if (da < db)      idx = ia;
    else if (db < da) idx = ib;
    else              idx = (ia < ib) ? ia : ib;   // tie: first index (argmin rule)

    out[p] = (float)idx;

    const float4* q4 = reinterpret_cast<const float4*>(emb + (size_t)idx * DIM);
    float4* oq = reinterpret_cast<float4*>(out + (size_t)NPTS + (size_t)p * DIM);
    float lsum = 0.f;
    #pragma unroll
    for (int i = 0; i < 32; ++i) {
        float4 qv = q4[i];
        oq[i] = qv;
        float dx = qv.x - xr[i].x;
        float dy = qv.y - xr[i].y;
        float dz = qv.z - xr[i].z;
        float dw = qv.w - xr[i].w;
        lsum += dx * dx + dy * dy + dz * dz + dw * dw;
    }
    __shared__ float red[4];
    #pragma unroll
    for (int o = 32; o > 0; o >>= 1) lsum += __shfl_down(lsum, o);
    int lane = threadIdx.x & 63, wvl = threadIdx.x >> 6;
    if (lane == 0) red[wvl] = lsum;
    __syncthreads();
    if (threadIdx.x == 0) bsum[blockIdx.x] = (red[0] + red[1]) + (red[2] + red[3]);
}

__global__ void vq_finalize(const float* __restrict__ bsum, float* __restrict__ out) {
    __shared__ float red[8];
    int t = threadIdx.x;  // 512 threads
    float v = bsum[t];
    #pragma unroll
    for (int o = 32; o > 0; o >>= 1) v += __shfl_down(v, o);
    if ((t & 63) == 0) red[t >> 6] = v;
    __syncthreads();
    if (t == 0) {
        float s = 0.f;
        #pragma unroll
        for (int i = 0; i < 8; ++i) s += red[i];
        out[(size_t)NPTS + (size_t)NPTS * DIM] = 1.25f * s / 16777216.0f;
    }
}

// ---------------- fallback (round-2 proven path) ----------------
__global__ __launch_bounds__(256, 1) void vq_main(const float* __restrict__ x,
                                                  const float* __restrict__ emb,
                                                  const float* __restrict__ ee,
                                                  float* __restrict__ out,
                                                  float* __restrict__ bsum) {
    const int p = blockIdx.x * 256 + threadIdx.x;
    float4 xr[32];
    const float4* xv = reinterpret_cast<const float4*>(x + (size_t)p * DIM);
    #pragma unroll
    for (int i = 0; i < 32; ++i) xr[i] = xv[i];
    float bestv = -3.4e38f; int bi = 0;
    for (int k = 0; k < KC; ++k) {
        const int ku = __builtin_amdgcn_readfirstlane(k);
        const float4* e4 = reinterpret_cast<const float4*>(emb + (size_t)ku * DIM);
        float a0 = 0.f, a1 = 0.f, a2 = 0.f, a3 = 0.f;
        #pragma unroll
        for (int i = 0; i < 32; ++i) {
            float4 ev = e4[i];
            a0 = fmaf(xr[i].x, ev.x, a0);
            a1 = fmaf(xr[i].y, ev.y, a1);
            a2 = fmaf(xr[i].z, ev.z, a2);
            a3 = fmaf(xr[i].w, ev.w, a3);
        }
        float s = ((a0 + a1) + (a2 + a3)) - ee[ku];
        if (s > bestv) { bestv = s; bi = k; }
    }
    out[p] = (float)bi;
    const float4* q4 = reinterpret_cast<const float4*>(emb + (size_t)bi * DIM);
    float4* oq = reinterpret_cast<float4*>(out + (size_t)NPTS + (size_t)p * DIM);
    float lsum = 0.f;
    #pragma unroll
    for (int i = 0; i < 32; ++i) {
        float4 qv = q4[i];
        oq[i] = qv;
        float dx = qv.x - xr[i].x;
        float dy = qv.y - xr[i].y;
        float dz = qv.z - xr[i].z;
        float dw = qv.w - xr[i].w;
        lsum += dx * dx + dy * dy + dz * dz + dw * dw;
    }
    __shared__ float red[4];
    #pragma unroll
    for (int o = 32; o > 0; o >>= 1) lsum += __shfl_down(lsum, o);
    int lane = threadIdx.x & 63, wvl = threadIdx.x >> 6;
    if (lane == 0) red[wvl] = lsum;
    __syncthreads();
    if (threadIdx.x == 0) bsum[blockIdx.x] = (red[0] + red[1]) + (red[2] + red[3]);
}

extern "C" void kernel_launch(void* const* d_in, const int* in_sizes, int n_in,
                              void* d_out, int out_size, void* d_ws, size_t ws_size,
                              hipStream_t stream) {
    const float* x   = (const float*)d_in[0];
    const float* emb = (const float*)d_in[1];
    float* out = (float*)d_out;
    char*  ws  = (char*)d_ws;

    if (ws_size >= 1054720) {
        unsigned short* wsE = (unsigned short*)ws;          // 512 KB image
        float* ee   = (float*)(ws + 524288);                // 4 KB
        int*   best = (int*)(ws + 528384);                  // 512 KB
        float* bsum = (float*)(ws + 1052672);               // 2 KB
        vq_prep<<<512, 256, 0, stream>>>(emb, wsE);
        vq_ee<<<256, 256, 0, stream>>>(emb, ee);
        vq_mfma<<<1024, 256, 0, stream>>>(x, wsE, ee, best);
        vq_fin<<<512, 256, 0, stream>>>(x, emb, best, out, bsum);
        vq_finalize<<<1, 512, 0, stream>>>(bsum, out);
    } else {
        float* ee   = (float*)ws;
        float* bsum = (float*)ws + 1024;
        vq_ee<<<256, 256, 0, stream>>>(emb, ee);
        vq_main<<<512, 256, 0, stream>>>(x, emb, ee, out, bsum);
        vq_finalize<<<1, 512, 0, stream>>>(bsum, out);
    }
}